// Round 1
// baseline (109.561 us; speedup 1.0000x reference)
//
#include <hip/hip_runtime.h>

#define D_OUT 1024
#define BATCH 65536
#define NBLOCKS 2048

// fast tanh: (e^{2v}-1)/(e^{2v}+1) with hardware exp + rcp.
// clamp to +-9 so e^{2v} stays finite (e^18 ~ 6.6e7); rel err ~1e-6.
__device__ __forceinline__ float ftanh(float v) {
    v = fminf(fmaxf(v, -9.0f), 9.0f);
    float e = __expf(2.0f * v);
    return (e - 1.0f) * __builtin_amdgcn_rcpf(e + 1.0f);
}

__device__ __forceinline__ float4 affine4(float4 h, float4 w, float4 b) {
    float4 r;
    r.x = fmaf(h.x, w.x, b.x);
    r.y = fmaf(h.y, w.y, b.y);
    r.z = fmaf(h.z, w.z, b.z);
    r.w = fmaf(h.w, w.w, b.w);
    return r;
}

__device__ __forceinline__ float4 tanh4(float4 h) {
    float4 r;
    r.x = ftanh(h.x);
    r.y = ftanh(h.y);
    r.z = ftanh(h.z);
    r.w = ftanh(h.w);
    return r;
}

__global__ __launch_bounds__(256, 4) void OneToOneDeepNet_kernel(
        const float* __restrict__ x,
        const float* __restrict__ W,
        const float* __restrict__ B,
        float* __restrict__ out) {
    const int t = threadIdx.x;      // 0..255
    const int col4 = t << 2;        // this thread's 4 columns

    // Per-channel params: 4 layers x (w,b) x float4 = 32 VGPRs, loaded once.
    const float4 w0 = *(const float4*)(W + 0 * D_OUT + col4);
    const float4 w1 = *(const float4*)(W + 1 * D_OUT + col4);
    const float4 w2 = *(const float4*)(W + 2 * D_OUT + col4);
    const float4 w3 = *(const float4*)(W + 3 * D_OUT + col4);
    const float4 b0 = *(const float4*)(B + 0 * D_OUT + col4);
    const float4 b1 = *(const float4*)(B + 1 * D_OUT + col4);
    const float4 b2 = *(const float4*)(B + 2 * D_OUT + col4);
    const float4 b3 = *(const float4*)(B + 3 * D_OUT + col4);

    // One block-iteration = one full row (256 threads * 4 cols = 1024).
    for (int row = blockIdx.x; row < BATCH; row += NBLOCKS) {
        const size_t off = (size_t)row * D_OUT + col4;
        float4 h = *(const float4*)(x + off);
        h = tanh4(affine4(h, w0, b0));
        h = tanh4(affine4(h, w1, b1));
        h = tanh4(affine4(h, w2, b2));
        h = affine4(h, w3, b3);
        *(float4*)(out + off) = h;
    }
}

extern "C" void kernel_launch(void* const* d_in, const int* in_sizes, int n_in,
                              void* d_out, int out_size, void* d_ws, size_t ws_size,
                              hipStream_t stream) {
    const float* x = (const float*)d_in[0];
    const float* W = (const float*)d_in[1];
    const float* B = (const float*)d_in[2];
    float* out = (float*)d_out;
    OneToOneDeepNet_kernel<<<NBLOCKS, 256, 0, stream>>>(x, W, B, out);
}